// Round 6
// baseline (1826.830 us; speedup 1.0000x reference)
//
#include <hip/hip_runtime.h>
#include <hip/hip_bf16.h>

typedef short v8s __attribute__((ext_vector_type(8)));
typedef float v4f __attribute__((ext_vector_type(4)));

#define NLEV 254    // level lists for s=2..255
#define SPLIT 6     // s<SPLIT: stream-ordered launches; s>=SPLIT: 64-WG persistent

__device__ __forceinline__ float bf2f(unsigned short u) {
    union { unsigned int i; float f; } v; v.i = ((unsigned int)u) << 16; return v.f;
}
__device__ __forceinline__ unsigned short f2bf(float f) {
    union { float f; unsigned int i; } v; v.f = f;
    unsigned int x = v.i;
    return (unsigned short)((x + 0x7fffu + ((x >> 16) & 1u)) >> 16);
}
__device__ __forceinline__ float sigf(float x) { return __fdividef(1.f, 1.f + __expf(-x)); }
__device__ __forceinline__ float tanhfast(float x) { return 1.f - __fdividef(2.f, __expf(2.f * x) + 1.f); }

// async global->LDS, 16B per lane; LDS dst is wave-uniform base + lane*16
__device__ __forceinline__ void gld_lds16(const unsigned short* g, unsigned short* l) {
    __builtin_amdgcn_global_load_lds(
        (const __attribute__((address_space(1))) unsigned int*)g,
        (__attribute__((address_space(3))) unsigned int*)l, 16, 0, 0);
}

// ---------------------------------------------------------------------------
// m97-style GEMM: C[M,Npad] = act(A[M,512] @ W[Npad,512]^T + b1 (+b2)), bf16.
// 128x128 tile, BK=32, global_load_lds staging, XOR-swizzled k-blocks.
// ---------------------------------------------------------------------------
template <bool TANH>
__global__ __launch_bounds__(256)
void gemm128(const unsigned short* __restrict__ Ag, const unsigned short* __restrict__ Wg,
             const float* __restrict__ b1, const float* __restrict__ b2,
             unsigned short* __restrict__ Cg, int Nreal, int Npad)
{
    __shared__ __align__(16) unsigned short As[128 * 32];
    __shared__ __align__(16) unsigned short Bs[128 * 32];
    const int tid  = threadIdx.x;
    const int w    = tid >> 6;
    const int lane = tid & 63;
    const int quad = lane >> 4;
    const int lr   = lane & 15;
    const int wm   = w & 1, wn = w >> 1;
    const int m0   = blockIdx.y * 128;
    const int n0   = blockIdx.x * 128;

    const int srow = lane >> 2;
    const int kblk = (lane & 3) ^ ((lane >> 3) & 3);

    const unsigned short* gA0 = Ag + (size_t)(m0 + w * 16 + srow) * 512 + kblk * 8;
    const unsigned short* gA1 = gA0 + (size_t)64 * 512;
    const unsigned short* gB0 = Wg + (size_t)(n0 + w * 16 + srow) * 512 + kblk * 8;
    const unsigned short* gB1 = gB0 + (size_t)64 * 512;
    unsigned short* lA0 = As + (w * 16) * 32;
    unsigned short* lA1 = As + (64 + w * 16) * 32;
    unsigned short* lB0 = Bs + (w * 16) * 32;
    unsigned short* lB1 = Bs + (64 + w * 16) * 32;

    const int swz = (quad ^ ((lr >> 1) & 3)) * 8;
    int aoff[4], boff[4];
    #pragma unroll
    for (int i = 0; i < 4; ++i) {
        aoff[i] = (wm * 64 + i * 16 + lr) * 32 + swz;
        boff[i] = (wn * 64 + i * 16 + lr) * 32 + swz;
    }

    v4f zz = {0.f, 0.f, 0.f, 0.f};
    v4f acc[4][4] = {{zz,zz,zz,zz},{zz,zz,zz,zz},{zz,zz,zz,zz},{zz,zz,zz,zz}};

    for (int k = 0; k < 16; ++k) {
        __syncthreads();
        gld_lds16(gA0 + k * 32, lA0);
        gld_lds16(gA1 + k * 32, lA1);
        gld_lds16(gB0 + k * 32, lB0);
        gld_lds16(gB1 + k * 32, lB1);
        __syncthreads();
        v8s a[4], b[4];
        #pragma unroll
        for (int i = 0; i < 4; ++i) { a[i] = *(const v8s*)&As[aoff[i]]; b[i] = *(const v8s*)&Bs[boff[i]]; }
        #pragma unroll
        for (int i = 0; i < 4; ++i)
            #pragma unroll
            for (int j = 0; j < 4; ++j)
                acc[i][j] = __builtin_amdgcn_mfma_f32_16x16x32_bf16(a[i], b[j], acc[i][j], 0, 0, 0);
    }

    #pragma unroll
    for (int j = 0; j < 4; ++j) {
        const int nn = n0 + wn * 64 + j * 16 + lr;
        const float bias = (nn < Nreal) ? (b1[nn] + (b2 ? b2[nn] : 0.f)) : 0.f;
        #pragma unroll
        for (int i = 0; i < 4; ++i) {
            #pragma unroll
            for (int r = 0; r < 4; ++r) {
                const int mm = m0 + wm * 64 + i * 16 + quad * 4 + r;
                float v = acc[i][j][r] + bias;
                if (TANH) v = tanhfast(v);
                Cg[(size_t)mm * Npad + nn] = f2bf(v);
            }
        }
    }
}

// fp32 -> bf16, 8 elems/thread (n must be multiple of 2048)
__global__ void cvt8(const float* __restrict__ src, unsigned short* __restrict__ dst)
{
    const size_t i = ((size_t)blockIdx.x * 256 + threadIdx.x) * 8;
    float4 f0 = *(const float4*)(src + i);
    float4 f1 = *(const float4*)(src + i + 4);
    unsigned short t8[8];
    t8[0]=f2bf(f0.x); t8[1]=f2bf(f0.y); t8[2]=f2bf(f0.z); t8[3]=f2bf(f0.w);
    t8[4]=f2bf(f1.x); t8[5]=f2bf(f1.y); t8[6]=f2bf(f1.z); t8[7]=f2bf(f1.w);
    *(v8s*)(dst + i) = *(const v8s*)t8;
}

// Wa2 (1000x512 fp32) -> zero-padded 1024x512 bf16
__global__ void wa2pad(const float* __restrict__ src, unsigned short* __restrict__ dst)
{
    const int i = blockIdx.x * 256 + threadIdx.x;
    const int row = i >> 9;
    dst[i] = (row < 1000) ? f2bf(src[(size_t)row * 512 + (i & 511)]) : (unsigned short)0;
}

// Wfb[n][0:512]=Wih[n], Wfb[n][512:1024]=Whh[n]  (2048 x 1024 bf16)
__global__ void fuse_w(const float* __restrict__ Wih, const float* __restrict__ Whh,
                       unsigned short* __restrict__ Wfb)
{
    const size_t i = ((size_t)blockIdx.x * 256 + threadIdx.x) * 8;   // over 2048*1024
    const int n = (int)(i >> 10);
    const int c = (int)(i & 1023);
    const float* src = (c < 512) ? (Wih + (size_t)n * 512 + c) : (Whh + (size_t)n * 512 + (c - 512));
    float4 f0 = *(const float4*)(src);
    float4 f1 = *(const float4*)(src + 4);
    unsigned short t8[8];
    t8[0]=f2bf(f0.x); t8[1]=f2bf(f0.y); t8[2]=f2bf(f0.z); t8[3]=f2bf(f0.w);
    t8[4]=f2bf(f1.x); t8[5]=f2bf(f1.y); t8[6]=f2bf(f1.z); t8[7]=f2bf(f1.w);
    *(v8s*)(Wfb + i) = *(const v8s*)t8;
}

__global__ void bias_sum(const float* __restrict__ a, const float* __restrict__ b,
                         float* __restrict__ o)
{
    const int i = blockIdx.x * 256 + threadIdx.x;   // 2048
    o[i] = a[i] + b[i];
}

// masked initial state (bf16) + zero row buffer
__global__ void init_state(const float* __restrict__ h0, const float* __restrict__ c0,
                           const int* __restrict__ done,
                           unsigned short* __restrict__ h_init, unsigned short* __restrict__ c_init,
                           unsigned short* __restrict__ zbuf)
{
    const int b = blockIdx.x;
    const float m = 1.f - (float)done[b];
    for (int k = threadIdx.x; k < 512; k += 256) {
        h_init[(size_t)b * 512 + k] = f2bf(h0[(size_t)b * 512 + k] * m);
        c_init[(size_t)b * 512 + k] = f2bf(c0[(size_t)b * 512 + k] * m);
        if (b == 0) zbuf[k] = 0;
    }
}

// ---------------------------------------------------------------------------
// Segment prep (single WG): rel-step s(t,b)=0 if (t==0||done) else s+1.
// Deterministic row lists for s<2; level-grouped lists for s>=2; maxS; bar=0.
// ---------------------------------------------------------------------------
__global__ __launch_bounds__(256, 1)
void seg_prep(const int* __restrict__ done, int* __restrict__ rows,
              int* __restrict__ counts, int* __restrict__ offs,
              int* __restrict__ trows, int* __restrict__ tcnt, int* __restrict__ toffs,
              int* __restrict__ maxS, int* __restrict__ bar, int T)
{
    __shared__ unsigned int   bits[256][8];
    __shared__ unsigned short cnt[256][2];
    __shared__ unsigned short base[256][2];
    __shared__ int tot[2];
    __shared__ int goff[2];
    __shared__ int tcl[NLEV];
    __shared__ int tol[NLEV];
    __shared__ int tpos[NLEV];
    __shared__ int mxl[256];
    const int b = threadIdx.x;
    cnt[b][0] = 0; cnt[b][1] = 0;
    #pragma unroll
    for (int i = 0; i < 8; ++i) bits[b][i] = 0;
    for (int l = b; l < NLEV; l += 256) { tcl[l] = 0; tpos[l] = 0; }
    __syncthreads();

    int s = 0, mx = 0;
    for (int t = 0; t < T; ++t) {
        int d = done[t * 256 + b];
        if (d) bits[b][t >> 5] |= (1u << (t & 31));
        s = (t == 0 || d) ? 0 : s + 1;
        if (s < 2) cnt[b][s]++;
        else atomicAdd(&tcl[s - 2], 1);
        mx = mx > s ? mx : s;
    }
    mxl[b] = mx;
    __syncthreads();

    if (b < 2) {
        int tsum = 0;
        for (int bb = 0; bb < 256; ++bb) { base[bb][b] = (unsigned short)tsum; tsum += cnt[bb][b]; }
        tot[b] = tsum;
    }
    __syncthreads();
    if (b == 0) {
        goff[0] = 0; goff[1] = tot[0];
        int run = 0;
        for (int l = 0; l < NLEV; ++l) { tol[l] = run; run += tcl[l]; }
        int m = 0;
        for (int bb = 0; bb < 256; ++bb) m = m > mxl[bb] ? m : mxl[bb];
        *maxS = m;
        *bar  = 0;
    }
    __syncthreads();
    if (b < 2) { counts[b] = tot[b]; offs[b] = goff[b]; }
    for (int l = b; l < NLEV; l += 256) { tcnt[l] = tcl[l]; toffs[l] = tol[l]; }

    s = 0;
    for (int t = 0; t < T; ++t) {
        int d = (bits[b][t >> 5] >> (t & 31)) & 1;
        s = (t == 0 || d) ? 0 : s + 1;
        if (s < 2) {
            int idx = goff[s] + (int)base[b][s];
            base[b][s]++;
            rows[idx] = t * 256 + b;
        } else {
            int idx = tol[s - 2] + atomicAdd(&tpos[s - 2], 1);
            trows[idx] = t * 256 + b;
        }
    }
}

// ---------------------------------------------------------------------------
// Fused LSTM tile: 128 gathered rows x (4 gates x 32 hidden cols), K=1024
// over [H2_row || h_prev_row] @ [Wih|Whh]^T. Gates exchanged in LDS; cell
// update + NH=h+H2 fused in epilogue. MODE 0: s==0 (h_init/c_init/zbuf);
// MODE 1: s>=1 (Hraw/Cst).
// ---------------------------------------------------------------------------
template <int MODE>
__device__ __forceinline__ void lstm_tile(
    const int* __restrict__ rlist, int M, int mt, int c0,
    const unsigned short* __restrict__ H2g, const unsigned short* __restrict__ Wfb,
    const float* __restrict__ bsum,
    const unsigned short* __restrict__ h_init, const unsigned short* __restrict__ c_init,
    const unsigned short* __restrict__ zbuf,
    unsigned short* __restrict__ Hraw, unsigned short* __restrict__ Cst,
    unsigned short* __restrict__ NH,
    unsigned short* As, unsigned short* Bs, unsigned short* Gx, int* rl)
{
    const int tid  = threadIdx.x;
    const int w    = tid >> 6;
    const int lane = tid & 63;
    const int quad = lane >> 4;
    const int lr   = lane & 15;
    const int wm   = w & 1, wn = w >> 1;
    const int srow = lane >> 2;
    const int kblk = (lane & 3) ^ ((lane >> 3) & 3);

    __syncthreads();                 // prior tile's LDS readers done
    if (tid < 128) {
        int li = mt * 128 + tid;
        rl[tid] = (li < M) ? rlist[li] : -1;
    }
    __syncthreads();

    const int g0r = rl[w * 16 + srow];
    const int g1r = rl[64 + w * 16 + srow];
    const unsigned short* gX0 = (g0r >= 0) ? H2g + (size_t)g0r * 512 + kblk * 8 : zbuf + kblk * 8;
    const unsigned short* gX1 = (g1r >= 0) ? H2g + (size_t)g1r * 512 + kblk * 8 : zbuf + kblk * 8;
    const unsigned short* gH0;
    const unsigned short* gH1;
    if (MODE == 0) {
        gH0 = (g0r >= 0 && g0r < 256) ? h_init + (size_t)g0r * 512 + kblk * 8 : zbuf + kblk * 8;
        gH1 = (g1r >= 0 && g1r < 256) ? h_init + (size_t)g1r * 512 + kblk * 8 : zbuf + kblk * 8;
    } else {
        gH0 = (g0r >= 0) ? Hraw + (size_t)(g0r - 256) * 512 + kblk * 8 : zbuf + kblk * 8;
        gH1 = (g1r >= 0) ? Hraw + (size_t)(g1r - 256) * 512 + kblk * 8 : zbuf + kblk * 8;
    }
    const int br0 = w * 16 + srow;
    const int br1 = 64 + br0;
    const unsigned short* gB0 = Wfb + (size_t)((br0 >> 5) * 512 + c0 + (br0 & 31)) * 1024 + kblk * 8;
    const unsigned short* gB1 = Wfb + (size_t)((br1 >> 5) * 512 + c0 + (br1 & 31)) * 1024 + kblk * 8;
    unsigned short* lA0 = As + (w * 16) * 32;
    unsigned short* lA1 = As + (64 + w * 16) * 32;
    unsigned short* lB0 = Bs + (w * 16) * 32;
    unsigned short* lB1 = Bs + (64 + w * 16) * 32;

    const int swz = (quad ^ ((lr >> 1) & 3)) * 8;
    int aoff[4], boff[4];
    #pragma unroll
    for (int i = 0; i < 4; ++i) {
        aoff[i] = (wm * 64 + i * 16 + lr) * 32 + swz;
        boff[i] = (wn * 64 + i * 16 + lr) * 32 + swz;
    }

    v4f zz = {0.f, 0.f, 0.f, 0.f};
    v4f acc[4][4] = {{zz,zz,zz,zz},{zz,zz,zz,zz},{zz,zz,zz,zz},{zz,zz,zz,zz}};

    // half 0: x-part (A=H2 rows, W cols 0..511); half 1: h-part (A=h_prev, W cols 512..1023)
    #pragma unroll 1
    for (int half = 0; half < 2; ++half) {
        const unsigned short* pa0 = half ? gH0 : gX0;
        const unsigned short* pa1 = half ? gH1 : gX1;
        const unsigned short* pb0 = gB0 + half * 512;
        const unsigned short* pb1 = gB1 + half * 512;
        for (int k = 0; k < 16; ++k) {
            __syncthreads();
            gld_lds16(pa0 + k * 32, lA0);
            gld_lds16(pa1 + k * 32, lA1);
            gld_lds16(pb0 + k * 32, lB0);
            gld_lds16(pb1 + k * 32, lB1);
            __syncthreads();
            v8s a[4], b[4];
            #pragma unroll
            for (int i = 0; i < 4; ++i) { a[i] = *(const v8s*)&As[aoff[i]]; b[i] = *(const v8s*)&Bs[boff[i]]; }
            #pragma unroll
            for (int i = 0; i < 4; ++i)
                #pragma unroll
                for (int j = 0; j < 4; ++j)
                    acc[i][j] = __builtin_amdgcn_mfma_f32_16x16x32_bf16(a[i], b[j], acc[i][j], 0, 0, 0);
        }
    }

    // publish gate pre-activations to LDS (bf16)
    #pragma unroll
    for (int j = 0; j < 4; ++j) {
        const int nl = wn * 64 + j * 16 + lr;
        #pragma unroll
        for (int i = 0; i < 4; ++i)
            #pragma unroll
            for (int r = 0; r < 4; ++r)
                Gx[(wm * 64 + i * 16 + quad * 4 + r) * 136 + nl] = f2bf(acc[i][j][r]);
    }
    __syncthreads();

    // fused cell update: thread owns row tid>>1, 16 hidden cols (2 chunks of 8)
    {
        const int rloc = tid >> 1;
        const int halfc = tid & 1;
        const int gr   = rl[rloc];
        if (gr >= 0) {
            #pragma unroll
            for (int ch = 0; ch < 2; ++ch) {
                const int co = halfc * 16 + ch * 8;
                const int kg = c0 + co;
                v8s q0 = *(const v8s*)&Gx[rloc * 136 +   0 + co];
                v8s q1 = *(const v8s*)&Gx[rloc * 136 +  32 + co];
                v8s q2 = *(const v8s*)&Gx[rloc * 136 +  64 + co];
                v8s q3 = *(const v8s*)&Gx[rloc * 136 +  96 + co];
                float4 bi0 = *(const float4*)&bsum[kg];          float4 bi1 = *(const float4*)&bsum[kg + 4];
                float4 bf0 = *(const float4*)&bsum[512 + kg];    float4 bf1 = *(const float4*)&bsum[512 + kg + 4];
                float4 bg0 = *(const float4*)&bsum[1024 + kg];   float4 bg1 = *(const float4*)&bsum[1024 + kg + 4];
                float4 bo0 = *(const float4*)&bsum[1536 + kg];   float4 bo1 = *(const float4*)&bsum[1536 + kg + 4];
                float bi[8] = {bi0.x,bi0.y,bi0.z,bi0.w,bi1.x,bi1.y,bi1.z,bi1.w};
                float bf[8] = {bf0.x,bf0.y,bf0.z,bf0.w,bf1.x,bf1.y,bf1.z,bf1.w};
                float bg[8] = {bg0.x,bg0.y,bg0.z,bg0.w,bg1.x,bg1.y,bg1.z,bg1.w};
                float bo[8] = {bo0.x,bo0.y,bo0.z,bo0.w,bo1.x,bo1.y,bo1.z,bo1.w};
                float cprev[8];
                if (MODE == 0) {
                    if (gr < 256) {
                        v8s cv = *(const v8s*)&c_init[(size_t)gr * 512 + kg];
                        #pragma unroll
                        for (int e = 0; e < 8; ++e) cprev[e] = bf2f((unsigned short)cv[e]);
                    } else {
                        #pragma unroll
                        for (int e = 0; e < 8; ++e) cprev[e] = 0.f;
                    }
                } else {
                    v8s cv = *(const v8s*)&Cst[(size_t)(gr - 256) * 512 + kg];
                    #pragma unroll
                    for (int e = 0; e < 8; ++e) cprev[e] = bf2f((unsigned short)cv[e]);
                }
                v8s h2v = *(const v8s*)&H2g[(size_t)gr * 512 + kg];
                unsigned short hc[8], cc[8], nhc[8];
                #pragma unroll
                for (int e = 0; e < 8; ++e) {
                    float gi = bf2f((unsigned short)q0[e]) + bi[e];
                    float gf = bf2f((unsigned short)q1[e]) + bf[e];
                    float gg = bf2f((unsigned short)q2[e]) + bg[e];
                    float go = bf2f((unsigned short)q3[e]) + bo[e];
                    float c  = sigf(gf) * cprev[e] + sigf(gi) * tanhfast(gg);
                    float h  = sigf(go) * tanhfast(c);
                    cc[e]  = f2bf(c);
                    hc[e]  = f2bf(h);
                    nhc[e] = f2bf(h + bf2f((unsigned short)h2v[e]));
                }
                *(v8s*)&Cst[(size_t)gr * 512 + kg]  = *(const v8s*)cc;
                *(v8s*)&Hraw[(size_t)gr * 512 + kg] = *(const v8s*)hc;
                *(v8s*)&NH[(size_t)gr * 512 + kg]   = *(const v8s*)nhc;
            }
        }
    }
}

// one level (stream-ordered): grid (16 col-blocks, Y m-tiles)
template <int MODE>
__global__ __launch_bounds__(256)
void lstm_round(const int* __restrict__ rows, const int* __restrict__ counts,
                const int* __restrict__ offs, int idx,
                const unsigned short* __restrict__ H2g, const unsigned short* __restrict__ Wfb,
                const float* __restrict__ bsum,
                const unsigned short* __restrict__ h_init, const unsigned short* __restrict__ c_init,
                const unsigned short* __restrict__ zbuf,
                unsigned short* __restrict__ Hraw, unsigned short* __restrict__ Cst,
                unsigned short* __restrict__ NH)
{
    const int M = counts[idx];
    if (M == 0) return;
    const int off    = offs[idx];
    const int mtiles = (M + 127) >> 7;
    __shared__ __align__(16) unsigned short As[128 * 32];
    __shared__ __align__(16) unsigned short Bs[128 * 32];
    __shared__ __align__(16) unsigned short Gx[128 * 136];
    __shared__ int rl[128];
    const int c0 = blockIdx.x * 32;
    for (int mt = blockIdx.y; mt < mtiles; mt += gridDim.y)
        lstm_tile<MODE>(rows + off, M, mt, c0, H2g, Wfb, bsum, h_init, c_init, zbuf,
                        Hraw, Cst, NH, As, Bs, Gx, rl);
}

// ---------------------------------------------------------------------------
// Persistent tail for s>=SPLIT: **64 WGs** (R4-proven co-residency), grid-
// stride tiles per level, agent-scope spin barrier between levels (monotone
// counter; seg_prep resets bar each call => graph-replay safe).
// ---------------------------------------------------------------------------
__global__ __launch_bounds__(256, 1)
void lstm_levels64(const int* __restrict__ trows, const int* __restrict__ tcnt,
                   const int* __restrict__ toffs, const int* __restrict__ maxS_p,
                   const unsigned short* __restrict__ H2g, const unsigned short* __restrict__ Wfb,
                   const float* __restrict__ bsum,
                   const unsigned short* __restrict__ zbuf,
                   unsigned short* __restrict__ Hraw, unsigned short* __restrict__ Cst,
                   unsigned short* __restrict__ NH, int* __restrict__ bar)
{
    const int mS = *maxS_p;
    if (mS < SPLIT) return;
    __shared__ __align__(16) unsigned short As[128 * 32];
    __shared__ __align__(16) unsigned short Bs[128 * 32];
    __shared__ __align__(16) unsigned short Gx[128 * 136];
    __shared__ int rl[128];
    const int tid = threadIdx.x;
    int target = 0;
    for (int s = SPLIT; s <= mS; ++s) {
        const int lev = s - 2;
        const int M   = tcnt[lev];
        if (M > 0) {
            const int off    = toffs[lev];
            const int mtiles = (M + 127) >> 7;
            const int ntiles = mtiles * 16;
            for (int tile = blockIdx.x; tile < ntiles; tile += 64) {
                const int mt = tile >> 4;
                const int c0 = (tile & 15) * 32;
                lstm_tile<1>(trows + off, M, mt, c0, H2g, Wfb, bsum, nullptr, nullptr, zbuf,
                             Hraw, Cst, NH, As, Bs, Gx, rl);
            }
        }
        target += 64;
        __threadfence();
        __syncthreads();
        if (tid == 0) {
            __hip_atomic_fetch_add(bar, 1, __ATOMIC_RELEASE, __HIP_MEMORY_SCOPE_AGENT);
            while (__hip_atomic_load(bar, __ATOMIC_ACQUIRE, __HIP_MEMORY_SCOPE_AGENT) < target) {}
        }
        __syncthreads();
        __threadfence();
    }
}

// actor head: one wave per row over bf16 logits (stride 1024, 1000 valid)
__global__ void head_reduce(const unsigned short* __restrict__ logits,
                            const int* __restrict__ action,
                            float* __restrict__ out, int TB)
{
    const int r = blockIdx.x * 4 + (threadIdx.x >> 6);
    const int lane = threadIdx.x & 63;
    const unsigned short* row = logits + (size_t)r * 1024;
    float m = -1e30f, Z = 0.f, S = 0.f;
    v8s v0 = *(const v8s*)&row[lane * 8];
    #pragma unroll
    for (int e = 0; e < 8; ++e) {
        float xv = bf2f((unsigned short)v0[e]);
        if (xv > m) { float sc = __expf(m - xv); Z *= sc; S *= sc; m = xv; }
        float ev = __expf(xv - m);
        Z += ev; S += xv * ev;
    }
    v8s v1 = *(const v8s*)&row[512 + lane * 8];
    #pragma unroll
    for (int e = 0; e < 8; ++e) {
        int c = 512 + lane * 8 + e;
        if (c < 1000) {
            float xv = bf2f((unsigned short)v1[e]);
            if (xv > m) { float sc = __expf(m - xv); Z *= sc; S *= sc; m = xv; }
            float ev = __expf(xv - m);
            Z += ev; S += xv * ev;
        }
    }
    #pragma unroll
    for (int offb = 32; offb > 0; offb >>= 1) {
        float m2 = __shfl_xor(m, offb);
        float Z2 = __shfl_xor(Z, offb);
        float S2 = __shfl_xor(S, offb);
        float M  = fmaxf(m, m2);
        float s1 = __expf(m - M), s2 = __expf(m2 - M);
        Z = Z * s1 + Z2 * s2;
        S = S * s1 + S2 * s2;
        m = M;
    }
    if (lane == 0) {
        float lse = m + __logf(Z);
        float xa  = bf2f(row[action[r]]);
        out[r]      = xa - lse;
        out[TB + r] = lse - __fdividef(S, Z);
    }
}

__global__ void critic_v(const unsigned short* __restrict__ C1, const float* __restrict__ Wc2,
                         const float* __restrict__ bc2, float* __restrict__ out, int TB)
{
    const int r = blockIdx.x * 4 + (threadIdx.x >> 6);
    const int lane = threadIdx.x & 63;
    const unsigned short* row = C1 + (size_t)r * 512;
    v8s hv = *(const v8s*)&row[lane * 8];
    float4 w0 = *(const float4*)&Wc2[lane * 8];
    float4 w1 = *(const float4*)&Wc2[lane * 8 + 4];
    float s = bf2f((unsigned short)hv[0]) * w0.x + bf2f((unsigned short)hv[1]) * w0.y +
              bf2f((unsigned short)hv[2]) * w0.z + bf2f((unsigned short)hv[3]) * w0.w +
              bf2f((unsigned short)hv[4]) * w1.x + bf2f((unsigned short)hv[5]) * w1.y +
              bf2f((unsigned short)hv[6]) * w1.z + bf2f((unsigned short)hv[7]) * w1.w;
    #pragma unroll
    for (int offb = 32; offb > 0; offb >>= 1) s += __shfl_xor(s, offb);
    if (lane == 0) out[2 * TB + r] = s + bc2[0];
}

extern "C" void kernel_launch(void* const* d_in, const int* in_sizes, int n_in,
                              void* d_out, int out_size, void* d_ws, size_t ws_size,
                              hipStream_t stream)
{
    const float* x    = (const float*)d_in[0];
    const int*  done  = (const int*)d_in[1];
    const int*  action= (const int*)d_in[2];
    const float* W_t1 = (const float*)d_in[4];
    const float* b_t1 = (const float*)d_in[5];
    const float* W_t2 = (const float*)d_in[6];
    const float* b_t2 = (const float*)d_in[7];
    const float* Wih  = (const float*)d_in[8];
    const float* Whh  = (const float*)d_in[9];
    const float* bih  = (const float*)d_in[10];
    const float* bhh  = (const float*)d_in[11];
    const float* Wa1  = (const float*)d_in[12];
    const float* ba1  = (const float*)d_in[13];
    const float* Wa2  = (const float*)d_in[14];
    const float* ba2  = (const float*)d_in[15];
    const float* Wc1  = (const float*)d_in[16];
    const float* bc1  = (const float*)d_in[17];
    const float* Wc2  = (const float*)d_in[18];
    const float* bc2  = (const float*)d_in[19];
    const float* h0   = (const float*)d_in[20];
    const float* c0   = (const float*)d_in[21];
    float* out = (float*)d_out;

    const int TB = in_sizes[1];      // 65536
    const int T  = TB / 256;         // 256

    const size_t MiB = 1024 * 1024;
    char* ws = (char*)d_ws;
    // [0,64) H1 (trunk) -> [0,128) logits (head) | [128,192) A1/C1 |
    // [192,256) Hraw (alias xbf pre-rounds) | [256,320) Cst | [320,384) H2 |
    // [384,448) NH | [448,~456) weights/meta
    unsigned short* H1     = (unsigned short*)(ws);
    unsigned short* logits = (unsigned short*)(ws);
    unsigned short* A1     = (unsigned short*)(ws + 128 * MiB);
    unsigned short* C1     = A1;
    unsigned short* Hraw   = (unsigned short*)(ws + 192 * MiB);
    unsigned short* xbf    = Hraw;
    unsigned short* Cst    = (unsigned short*)(ws + 256 * MiB);
    unsigned short* H2     = (unsigned short*)(ws + 320 * MiB);
    unsigned short* NH     = (unsigned short*)(ws + 384 * MiB);
    unsigned short* Wt1b   = (unsigned short*)(ws + 448 * MiB);
    unsigned short* Wt2b   = Wt1b + 512 * 512;
    unsigned short* Wfb    = Wt2b + 512 * 512;          // 2048 x 1024
    unsigned short* Wa1b   = Wfb + 2048 * 1024;
    unsigned short* Wc1b   = Wa1b + 512 * 512;
    unsigned short* Wa2b   = Wc1b + 512 * 512;          // 1024 x 512
    unsigned short* h_init = Wa2b + 1024 * 512;
    unsigned short* c_init = h_init + 256 * 512;
    unsigned short* zbuf   = c_init + 256 * 512;
    float* bsum = (float*)(zbuf + 512);
    int* rows   = (int*)(bsum + 2048);
    int* trows  = rows + 65536;
    int* counts = trows + 65536;
    int* offs   = counts + 2;
    int* tcnt   = offs + 2;
    int* toffs  = tcnt + NLEV;
    int* maxS   = toffs + NLEV;
    int* bar    = maxS + 1;

    dim3 blk(256);

    // conversions, fused weights, bias sum, init, segment lists
    cvt8<<<16384, blk, 0, stream>>>(x, xbf);
    cvt8<<<128,  blk, 0, stream>>>(W_t1, Wt1b);
    cvt8<<<128,  blk, 0, stream>>>(W_t2, Wt2b);
    cvt8<<<128,  blk, 0, stream>>>(Wa1,  Wa1b);
    cvt8<<<128,  blk, 0, stream>>>(Wc1,  Wc1b);
    fuse_w<<<1024, blk, 0, stream>>>(Wih, Whh, Wfb);
    wa2pad<<<2048, blk, 0, stream>>>(Wa2, Wa2b);
    bias_sum<<<8, blk, 0, stream>>>(bih, bhh, bsum);
    init_state<<<256, blk, 0, stream>>>(h0, c0, done, h_init, c_init, zbuf);
    seg_prep<<<1, blk, 0, stream>>>(done, rows, counts, offs, trows, tcnt, toffs, maxS, bar, T);

    // trunk
    gemm128<true ><<<dim3(4, 512), blk, 0, stream>>>(xbf, Wt1b, b_t1, nullptr, H1, 512, 512);
    gemm128<true ><<<dim3(4, 512), blk, 0, stream>>>(H1,  Wt2b, b_t2, nullptr, H2, 512, 512);

    // segment-parallel LSTM: stream-ordered fused rounds s=0..5, then
    // 64-WG persistent tail (R4-proven spin barrier) for s>=6
    lstm_round<0><<<dim3(16, 264), blk, 0, stream>>>(rows, counts, offs, 0, H2, Wfb, bsum,
                                                     h_init, c_init, zbuf, Hraw, Cst, NH);
    lstm_round<1><<<dim3(16, 132), blk, 0, stream>>>(rows, counts, offs, 1, H2, Wfb, bsum,
                                                     h_init, c_init, zbuf, Hraw, Cst, NH);
    static const int Ys[4] = {66, 33, 17, 9};
    for (int s = 2; s < SPLIT; ++s)
        lstm_round<1><<<dim3(16, Ys[s - 2]), blk, 0, stream>>>(trows, tcnt, toffs, s - 2,
                                                     H2, Wfb, bsum,
                                                     nullptr, nullptr, zbuf, Hraw, Cst, NH);
    lstm_levels64<<<64, blk, 0, stream>>>(trows, tcnt, toffs, maxS, H2, Wfb, bsum, zbuf,
                                          Hraw, Cst, NH, bar);

    // actor head
    gemm128<true ><<<dim3(4, 512), blk, 0, stream>>>(NH, Wa1b, ba1, nullptr, A1, 512, 512);
    gemm128<false><<<dim3(8, 512), blk, 0, stream>>>(A1, Wa2b, ba2, nullptr, logits, 1000, 1024);
    head_reduce<<<TB / 4, blk, 0, stream>>>(logits, action, out, TB);

    // critic head
    gemm128<true ><<<dim3(4, 512), blk, 0, stream>>>(NH, Wc1b, bc1, nullptr, C1, 512, 512);
    critic_v<<<TB / 4, blk, 0, stream>>>(C1, Wc2, bc2, out, TB);
}